// Round 3
// baseline (1726.052 us; speedup 1.0000x reference)
//
#include <hip/hip_runtime.h>
#include <math.h>

#define TSEQ 2048
#define EMB  1024
#define NH   16
#define HD   64
#define NB   2
#define L2E  1.4426950408889634f

#if defined(__has_builtin)
#if __has_builtin(__builtin_amdgcn_exp2f)
#define EXP2(x) __builtin_amdgcn_exp2f(x)
#else
#define EXP2(x) exp2f(x)
#endif
#else
#define EXP2(x) exp2f(x)
#endif

// ---------------------------------------------------------------------------
// GEMM NT: C[i,j] = sum_k A[i,k] * B[j,k] + bias[j]
// A: M x K row-major, B: N x K row-major.
// mode 0: C0[i*N + j] = val   (plain row-major output)
// mode 1: qkv scatter into C0=q, C1=k, C2=v with layout [B,H,T,hd];
//         q is pre-scaled by 0.125 (= 1/sqrt(hd), exact power of two).
// Tile: 64x64 per block (256 threads), 4x4 per thread, BK=16.
// ---------------------------------------------------------------------------
__global__ __launch_bounds__(256) void gemm_nt_kernel(
    const float* __restrict__ A, const float* __restrict__ B,
    const float* __restrict__ bias,
    float* __restrict__ C0, float* __restrict__ C1, float* __restrict__ C2,
    int M, int N, int K, int mode)
{
    __shared__ float As[16][68];   // [k][i] transposed tiles; 68 = 64 + 4 pad
    __shared__ float Bs[16][68];

    const int tid = threadIdx.x;
    const int i0 = blockIdx.x * 64;
    const int j0 = blockIdx.y * 64;
    const int ty = tid >> 4;         // 0..15 -> i sub-tile
    const int tx = tid & 15;         // 0..15 -> j sub-tile
    const int lr = tid >> 2;         // 0..63 row for staging
    const int lc = (tid & 3) << 2;   // 0,4,8,12 k-offset for staging

    const float* Ap = A + (size_t)(i0 + lr) * K + lc;
    const float* Bp = B + (size_t)(j0 + lr) * K + lc;

    float acc[4][4];
    #pragma unroll
    for (int r = 0; r < 4; ++r)
        #pragma unroll
        for (int c = 0; c < 4; ++c) acc[r][c] = 0.f;

    for (int k0 = 0; k0 < K; k0 += 16) {
        float4 av = *(const float4*)(Ap + k0);
        float4 bv = *(const float4*)(Bp + k0);
        As[lc+0][lr] = av.x; As[lc+1][lr] = av.y; As[lc+2][lr] = av.z; As[lc+3][lr] = av.w;
        Bs[lc+0][lr] = bv.x; Bs[lc+1][lr] = bv.y; Bs[lc+2][lr] = bv.z; Bs[lc+3][lr] = bv.w;
        __syncthreads();
        #pragma unroll
        for (int kk = 0; kk < 16; ++kk) {
            float4 a4 = *(const float4*)&As[kk][ty << 2];
            float4 b4 = *(const float4*)&Bs[kk][tx << 2];
            float ar[4] = {a4.x, a4.y, a4.z, a4.w};
            float br[4] = {b4.x, b4.y, b4.z, b4.w};
            #pragma unroll
            for (int r = 0; r < 4; ++r)
                #pragma unroll
                for (int c = 0; c < 4; ++c)
                    acc[r][c] = fmaf(ar[r], br[c], acc[r][c]);
        }
        __syncthreads();
    }

    const float4 bv4 = *(const float4*)&bias[j0 + (tx << 2)];
    #pragma unroll
    for (int r = 0; r < 4; ++r) {
        const int i = i0 + (ty << 2) + r;
        float4 val;
        val.x = acc[r][0] + bv4.x;
        val.y = acc[r][1] + bv4.y;
        val.z = acc[r][2] + bv4.z;
        val.w = acc[r][3] + bv4.w;
        if (mode == 0) {
            *(float4*)&C0[(size_t)i * N + j0 + (tx << 2)] = val;
        } else {
            const int j = j0 + (tx << 2);          // all 4 lanes in same 64-block
            const int which = j >> 10;
            const int e = j & (EMB - 1);
            const int h = e >> 6, d = e & (HD - 1);
            const int b = i >> 11, t = i & (TSEQ - 1);
            float* dst = (which == 0) ? C0 : (which == 1 ? C1 : C2);
            if (which == 0) { val.x *= 0.125f; val.y *= 0.125f; val.z *= 0.125f; val.w *= 0.125f; }
            *(float4*)&dst[(size_t)((b * NH + h) * TSEQ + t) * HD + d] = val;
        }
    }
}

// ---------------------------------------------------------------------------
// In-place rotary on k: k viewed as pairs (re,im) along hd; masks [B,1,T,hd/2].
// One thread per complex pair; pair index maps directly to k layout [B,H,T,hd].
// ---------------------------------------------------------------------------
__global__ __launch_bounds__(256) void rotary_k_kernel(
    float* __restrict__ k,
    const float* __restrict__ mre, const float* __restrict__ mim)
{
    const int idx = blockIdx.x * 256 + threadIdx.x;   // 0 .. 2^21-1 pairs
    const int d2 = idx & 31;
    const int t  = (idx >> 5) & (TSEQ - 1);
    const int b  = idx >> 20;                         // NH*TSEQ*32 = 2^20 per batch
    float2 kv = *(float2*)(k + ((size_t)idx << 1));
    const int mix = (b * TSEQ + t) * 32 + d2;
    const float mr = mre[mix], mi = mim[mix];
    float2 out;
    out.x = kv.x * mr - kv.y * mi;
    out.y = kv.x * mi + kv.y * mr;
    *(float2*)(k + ((size_t)idx << 1)) = out;
}

// ---------------------------------------------------------------------------
// Flash-style attention, 4 threads per q row (16 head-dims each).
// Block = 256 threads = 64 q rows of one (b,h); grid = 32 q-tiles x 32 (b,h)
// = 1024 blocks (~4 resident blocks/CU -> ~4 waves/SIMD for latency hiding).
// Scores via 4-lane __shfl_xor reduce; (m,l) kept redundantly (identical) in
// all 4 lanes of a group. K/V tiles of 16 keys staged in LDS.
// Writes o_tmp in [B,T,E] layout, plus per-row running max m and 1/l.
// ---------------------------------------------------------------------------
__global__ __launch_bounds__(256) void flash_attn_kernel(
    const float* __restrict__ q, const float* __restrict__ k,
    const float* __restrict__ v, const float* __restrict__ pad,
    float* __restrict__ o_tmp, float* __restrict__ m_out,
    float* __restrict__ linv_out)
{
    __shared__ float Ks[16][64];
    __shared__ float Vs[16][64];
    __shared__ float padv[16];

    const int tid  = threadIdx.x;
    const int bh   = blockIdx.x >> 5;                 // 0..31
    const int qt   = blockIdx.x & 31;                 // q tile of 64 rows
    const int row  = tid >> 2;                        // 0..63
    const int part = tid & 3;                         // 16-dim slice
    const int t    = (qt << 6) + row;
    const int b    = bh >> 4, h = bh & (NH - 1);

    // q slice for this thread: dims [part*16, part*16+16)
    const float* qp = q + ((size_t)bh * TSEQ + t) * HD + (part << 4);
    float qr[16];
    #pragma unroll
    for (int i = 0; i < 4; ++i) {
        float4 v4 = *(const float4*)(qp + (i << 2));
        qr[4*i+0] = v4.x; qr[4*i+1] = v4.y; qr[4*i+2] = v4.z; qr[4*i+3] = v4.w;
    }
    float O[16];
    #pragma unroll
    for (int i = 0; i < 16; ++i) O[i] = 0.f;
    float m = -1e30f, l = 0.f;

    const int lrow = tid >> 4;          // 0..15
    const int lcol = (tid & 15) << 2;   // 0..60
    const float* kbase = k + (size_t)bh * TSEQ * HD;
    const float* vbase = v + (size_t)bh * TSEQ * HD;

    for (int k0 = 0; k0 < TSEQ; k0 += 16) {
        *(float4*)&Ks[lrow][lcol] = *(const float4*)(kbase + (size_t)(k0 + lrow) * HD + lcol);
        *(float4*)&Vs[lrow][lcol] = *(const float4*)(vbase + (size_t)(k0 + lrow) * HD + lcol);
        if (tid < 16) padv[tid] = pad[b * TSEQ + k0 + tid];
        __syncthreads();

        float sj[16];
        #pragma unroll
        for (int j = 0; j < 16; ++j) {
            float a0 = 0.f, a1 = 0.f, a2 = 0.f, a3 = 0.f;
            #pragma unroll
            for (int i4 = 0; i4 < 4; ++i4) {
                float4 kv4 = *(const float4*)&Ks[j][(part << 4) + (i4 << 2)];
                a0 = fmaf(qr[4*i4+0], kv4.x, a0);
                a1 = fmaf(qr[4*i4+1], kv4.y, a1);
                a2 = fmaf(qr[4*i4+2], kv4.z, a2);
                a3 = fmaf(qr[4*i4+3], kv4.w, a3);
            }
            float partial = (a0 + a1) + (a2 + a3);
            partial += __shfl_xor(partial, 1);
            partial += __shfl_xor(partial, 2);
            sj[j] = partial + padv[j];
        }

        float tmax = sj[0];
        #pragma unroll
        for (int j = 1; j < 16; ++j) tmax = fmaxf(tmax, sj[j]);
        const float mn = fmaxf(m, tmax);
        const float c = EXP2((m - mn) * L2E);
        l *= c;
        #pragma unroll
        for (int d = 0; d < 16; ++d) O[d] *= c;
        #pragma unroll
        for (int j = 0; j < 16; ++j) {
            const float p = EXP2((sj[j] - mn) * L2E);
            l += p;
            #pragma unroll
            for (int i4 = 0; i4 < 4; ++i4) {
                float4 v4 = *(const float4*)&Vs[j][(part << 4) + (i4 << 2)];
                O[4*i4+0] = fmaf(p, v4.x, O[4*i4+0]);
                O[4*i4+1] = fmaf(p, v4.y, O[4*i4+1]);
                O[4*i4+2] = fmaf(p, v4.z, O[4*i4+2]);
                O[4*i4+3] = fmaf(p, v4.w, O[4*i4+3]);
            }
        }
        m = mn;
        __syncthreads();
    }

    const float inv = 1.f / l;
    float* op = o_tmp + ((size_t)(b * TSEQ + t)) * EMB + h * HD + (part << 4);
    #pragma unroll
    for (int i4 = 0; i4 < 4; ++i4) {
        float4 st;
        st.x = O[4*i4+0] * inv; st.y = O[4*i4+1] * inv;
        st.z = O[4*i4+2] * inv; st.w = O[4*i4+3] * inv;
        *(float4*)(op + (i4 << 2)) = st;
    }
    if (part == 0) {
        m_out[bh * TSEQ + t] = m;
        linv_out[bh * TSEQ + t] = inv;
    }
}

// ---------------------------------------------------------------------------
// a_avg[b,q,kk] = (1/H) * sum_h exp(s_hqk - m[h,q]) * linv[h,q]
// Block: (b, q-tile 32, k-tile 128), 256 threads as 8(ty) x 32(tx),
// 4x4 outputs per thread. Loops over all 16 heads, re-reading q/k tiles
// transposed (d-major) into LDS so both inner reads are ds_read_b128.
// ---------------------------------------------------------------------------
__global__ __launch_bounds__(256) void attn_avg_kernel(
    const float* __restrict__ q, const float* __restrict__ k,
    const float* __restrict__ pad, const float* __restrict__ m_arr,
    const float* __restrict__ linv_arr, float* __restrict__ a_avg)
{
    __shared__ float qT[64][36];    // [d][qi], pad 4
    __shared__ float kT[64][132];   // [d][kj], pad 4
    __shared__ float m_s[32], li_s[32];
    __shared__ float padv[128];

    const int tid = threadIdx.x;
    const int b  = blockIdx.z;
    const int q0 = blockIdx.y << 5;   // *32
    const int k0 = blockIdx.x << 7;   // *128
    const int tx = tid & 31;          // k sub
    const int ty = tid >> 5;          // 0..7 q sub

    if (tid < 128) padv[tid] = pad[b * TSEQ + k0 + tid];

    float sum[4][4];
    #pragma unroll
    for (int r = 0; r < 4; ++r)
        #pragma unroll
        for (int c = 0; c < 4; ++c) sum[r][c] = 0.f;

    for (int h = 0; h < NH; ++h) {
        __syncthreads();   // protect previous iteration's reads
        const size_t base = (size_t)(b * NH + h) * TSEQ;
        // q tile: 32 rows x 64 dims = 512 float4; 2 per thread
        #pragma unroll
        for (int it = 0; it < 2; ++it) {
            const int ff = tid + (it << 8);
            const int row = ff >> 4, c4 = (ff & 15) << 2;
            float4 v4 = *(const float4*)&q[(base + q0 + row) * HD + c4];
            qT[c4+0][row] = v4.x; qT[c4+1][row] = v4.y;
            qT[c4+2][row] = v4.z; qT[c4+3][row] = v4.w;
        }
        // k tile: 128 rows x 64 dims = 2048 float4; 8 per thread
        #pragma unroll
        for (int it = 0; it < 8; ++it) {
            const int ff = tid + (it << 8);
            const int row = ff >> 4, c4 = (ff & 15) << 2;
            float4 v4 = *(const float4*)&k[(base + k0 + row) * HD + c4];
            kT[c4+0][row] = v4.x; kT[c4+1][row] = v4.y;
            kT[c4+2][row] = v4.z; kT[c4+3][row] = v4.w;
        }
        if (tid < 32) {
            m_s[tid]  = m_arr[(b * NH + h) * TSEQ + q0 + tid];
            li_s[tid] = linv_arr[(b * NH + h) * TSEQ + q0 + tid];
        }
        __syncthreads();

        float acc[4][4];
        #pragma unroll
        for (int r = 0; r < 4; ++r)
            #pragma unroll
            for (int c = 0; c < 4; ++c) acc[r][c] = 0.f;

        for (int d = 0; d < 64; ++d) {
            float4 kq = *(const float4*)&kT[d][tx << 2];
            float4 qq = *(const float4*)&qT[d][ty << 2];
            float qa[4] = {qq.x, qq.y, qq.z, qq.w};
            float ka[4] = {kq.x, kq.y, kq.z, kq.w};
            #pragma unroll
            for (int r = 0; r < 4; ++r)
                #pragma unroll
                for (int c = 0; c < 4; ++c)
                    acc[r][c] = fmaf(qa[r], ka[c], acc[r][c]);
        }
        #pragma unroll
        for (int r = 0; r < 4; ++r) {
            const float mh = m_s[(ty << 2) + r];
            const float li = li_s[(ty << 2) + r];
            #pragma unroll
            for (int c = 0; c < 4; ++c) {
                const float s = acc[r][c] + padv[(tx << 2) + c];
                sum[r][c] = fmaf(EXP2((s - mh) * L2E), li, sum[r][c]);
            }
        }
    }

    const float invH = 1.0f / (float)NH;
    #pragma unroll
    for (int r = 0; r < 4; ++r) {
        const int row = q0 + (ty << 2) + r;
        float4 outv;
        outv.x = sum[r][0] * invH; outv.y = sum[r][1] * invH;
        outv.z = sum[r][2] * invH; outv.w = sum[r][3] * invH;
        *(float4*)&a_avg[((size_t)b * TSEQ + row) * TSEQ + k0 + (tx << 2)] = outv;
    }
}

// ---------------------------------------------------------------------------
extern "C" void kernel_launch(void* const* d_in, const int* in_sizes, int n_in,
                              void* d_out, int out_size, void* d_ws, size_t ws_size,
                              hipStream_t stream)
{
    const float* x    = (const float*)d_in[0];
    const float* mre  = (const float*)d_in[1];
    const float* mim  = (const float*)d_in[2];
    const float* pad  = (const float*)d_in[3];
    const float* qkvw = (const float*)d_in[4];
    const float* qkvb = (const float*)d_in[5];
    const float* ow   = (const float*)d_in[6];
    const float* ob   = (const float*)d_in[7];

    float* out_o = (float*)d_out;                    // [B,T,E] = 4194304 floats
    float* out_a = out_o + (size_t)NB * TSEQ * EMB;  // [B,T,T] = 8388608 floats

    // o_tmp borrows the a_avg output region (16 MB of its 32 MB): it is fully
    // consumed by the output-projection GEMM BEFORE attn_avg overwrites the
    // region with the real a_avg (stream-ordered kernels).
    float* otmp = out_a;

    // workspace layout (floats): q | k | v | m | linv  (~48.5 MB)
    float* w = (float*)d_ws;
    const size_t SZ = (size_t)NB * NH * TSEQ * HD;   // 4194304
    float* qb    = w;
    float* kb    = w + SZ;
    float* vb    = w + 2 * SZ;
    float* marr  = w + 3 * SZ;
    float* linv  = w + 3 * SZ + (size_t)NB * NH * TSEQ;

    // 1) fused QKV projection, scatter to [B,H,T,hd], q pre-scaled
    gemm_nt_kernel<<<dim3(64, 48), 256, 0, stream>>>(
        x, qkvw, qkvb, qb, kb, vb, NB * TSEQ, 3 * EMB, EMB, 1);

    // 2) rotary on k
    rotary_k_kernel<<<8192, 256, 0, stream>>>(kb, mre, mim);

    // 3) flash attention -> o_tmp [B,T,E], stats (m, 1/l)
    flash_attn_kernel<<<1024, 256, 0, stream>>>(qb, kb, vb, pad, otmp, marr, linv);

    // 4) output projection (consumes o_tmp from the a_avg region)
    gemm_nt_kernel<<<dim3(64, 16), 256, 0, stream>>>(
        otmp, ow, ob, out_o, nullptr, nullptr, NB * TSEQ, EMB, EMB, 0);

    // 5) head-averaged probs -> a_avg (overwrites the scratch region)
    attn_avg_kernel<<<dim3(TSEQ / 128, TSEQ / 32, NB), 256, 0, stream>>>(
        qb, kb, pad, marr, linv, out_a);
}